// Round 1
// baseline (11188.868 us; speedup 1.0000x reference)
//
#include <hip/hip_runtime.h>
#include <hip/hip_bf16.h>
#include <math.h>

// Problem constants (from reference): B=512, T=256, H=512, HALF=256, TGT=28
#define BB   512
#define TT   256
#define HH   512
#define HALF 256
#define TGT  28

__device__ __forceinline__ float sigmoidf_(float x) {
    return 1.0f / (1.0f + __expf(-x));
}
__device__ __forceinline__ float tanhf_(float x) {
    x = fminf(fmaxf(x, -15.0f), 15.0f);
    float e = __expf(-2.0f * x);
    return (1.0f - e) / (1.0f + e);
}

// prep: transpose W_hh [4H, H] (row-major, gate-major) into Wt2[k][j][g]
// (k = contraction index over H, j = hidden column 0..511, g = gate 0..3),
// and zero h0 / h1 / c (ws is poisoned with 0xAA before every launch).
__global__ __launch_bounds__(256) void prep_kernel(
    const float* __restrict__ Whh, float* __restrict__ Wt2,
    float* __restrict__ h0, float* __restrict__ h1, float* __restrict__ c)
{
    int tid = blockIdx.x * 256 + threadIdx.x;   // 0 .. 262143 (grid = 1024 x 256)
    h0[tid] = 0.0f;
    h1[tid] = 0.0f;
    c[tid]  = 0.0f;
    for (int idx = tid; idx < HH * HH * 4; idx += 262144) {
        int g = idx & 3;
        int j = (idx >> 2) & (HH - 1);
        int k = idx >> 11;                       // idx / (4*512)
        Wt2[idx] = Whh[(g * HH + j) * HH + k];
    }
}

// One LSTM timestep, fused GEMM + gate elementwise.
// Layouts: hprev/hnext/cT are transposed [j][b] (512 x 512).
// Wt2 is [k][j][g].
// Each thread: 4 batch rows x 1 hidden col x 4 gates (16 accumulators).
// Block: 256 threads = 16 j x 16 b-groups -> tile 16 j x 64 b.
// Grid: (512/16 j-tiles, 512/64 b-tiles) = (32, 8) = 256 blocks.
__global__ __launch_bounds__(256) void lstm_step(
    const float* __restrict__ Wt2,
    const float* __restrict__ hprev,
    float* __restrict__ hnext,
    float* __restrict__ cT,
    const float* __restrict__ seq,
    const float* __restrict__ wih,
    const float* __restrict__ bih,
    const float* __restrict__ bhh,
    int t)
{
    const int tx = threadIdx.x & 15;            // j within tile
    const int ty = threadIdx.x >> 4;            // b-group within tile
    const int j  = blockIdx.x * 16 + tx;        // hidden column
    const int b0 = blockIdx.y * 64 + ty * 4;    // first of 4 batch rows

    const float* wp = Wt2 + j * 4;              // row stride = 512*4 = 2048 floats
    const float* hp = hprev + b0;               // row stride = 512 floats

    float acc[4][4] = {{0.f}};

    #pragma unroll 4
    for (int k = 0; k < HH; ++k) {
        float4 wv = *(const float4*)wp;  wp += HH * 4;
        float4 hv = *(const float4*)hp;  hp += HH;
        const float h_[4] = {hv.x, hv.y, hv.z, hv.w};
        const float w_[4] = {wv.x, wv.y, wv.z, wv.w};
        #pragma unroll
        for (int r = 0; r < 4; ++r) {
            #pragma unroll
            for (int g = 0; g < 4; ++g) {
                acc[r][g] += h_[r] * w_[g];
            }
        }
    }

    // epilogue: gates -> (c, h) update. Gate order (i, f, g, o), col = gate*H + j.
    float bias[4], wx[4];
    #pragma unroll
    for (int g = 0; g < 4; ++g) {
        int col = g * HH + j;
        bias[g] = bih[col] + bhh[col];
        wx[g]   = wih[col];
    }

    float4 cv = *(const float4*)(cT + j * HH + b0);
    float carr[4] = {cv.x, cv.y, cv.z, cv.w};
    float hout[4], cout[4];

    #pragma unroll
    for (int r = 0; r < 4; ++r) {
        float x  = seq[(b0 + r) * TT + t];
        float gi = acc[r][0] + x * wx[0] + bias[0];
        float gf = acc[r][1] + x * wx[1] + bias[1];
        float gg = acc[r][2] + x * wx[2] + bias[2];
        float go = acc[r][3] + x * wx[3] + bias[3];
        float i_ = sigmoidf_(gi);
        float f_ = sigmoidf_(gf);
        float g_ = tanhf_(gg);
        float o_ = sigmoidf_(go);
        float cn = f_ * carr[r] + i_ * g_;
        cout[r]  = cn;
        hout[r]  = o_ * tanhf_(cn);
    }

    *(float4*)(cT    + j * HH + b0) = make_float4(cout[0], cout[1], cout[2], cout[3]);
    *(float4*)(hnext + j * HH + b0) = make_float4(hout[0], hout[1], hout[2], hout[3]);
}

// Final FC: hid = relu(h @ fc1_w.T + fc1_b); out = hid @ fc2_w.T + fc2_b
// One block per batch row. hT is [j][b] transposed.
__global__ __launch_bounds__(256) void fc_kernel(
    const float* __restrict__ hT,
    const float* __restrict__ fc1w, const float* __restrict__ fc1b,
    const float* __restrict__ fc2w, const float* __restrict__ fc2b,
    float* __restrict__ out)
{
    __shared__ float hS[HH];
    __shared__ float hidS[HALF];
    const int b = blockIdx.x, tid = threadIdx.x;

    hS[tid]       = hT[tid * HH + b];
    hS[tid + 256] = hT[(tid + 256) * HH + b];
    __syncthreads();

    float acc = fc1b[tid];
    const float4* wrow = (const float4*)(fc1w + tid * HH);
    #pragma unroll 4
    for (int k4 = 0; k4 < HH / 4; ++k4) {
        float4 w = wrow[k4];
        acc += w.x * hS[k4 * 4] + w.y * hS[k4 * 4 + 1]
             + w.z * hS[k4 * 4 + 2] + w.w * hS[k4 * 4 + 3];
    }
    hidS[tid] = fmaxf(acc, 0.0f);
    __syncthreads();

    if (tid < TGT) {
        float a2 = fc2b[tid];
        const float4* w2 = (const float4*)(fc2w + tid * HALF);
        #pragma unroll 4
        for (int k4 = 0; k4 < HALF / 4; ++k4) {
            float4 w = w2[k4];
            a2 += w.x * hidS[k4 * 4] + w.y * hidS[k4 * 4 + 1]
                + w.z * hidS[k4 * 4 + 2] + w.w * hidS[k4 * 4 + 3];
        }
        out[b * TGT + tid] = a2;
    }
}

extern "C" void kernel_launch(void* const* d_in, const int* in_sizes, int n_in,
                              void* d_out, int out_size, void* d_ws, size_t ws_size,
                              hipStream_t stream)
{
    const float* seq   = (const float*)d_in[0];  // [512,256,1]
    const float* W_ih  = (const float*)d_in[1];  // [2048,1]
    const float* W_hh  = (const float*)d_in[2];  // [2048,512]
    const float* b_ih  = (const float*)d_in[3];  // [2048]
    const float* b_hh  = (const float*)d_in[4];  // [2048]
    const float* fc1_w = (const float*)d_in[5];  // [256,512]
    const float* fc1_b = (const float*)d_in[6];  // [256]
    const float* fc2_w = (const float*)d_in[7];  // [28,256]
    const float* fc2_b = (const float*)d_in[8];  // [28]
    float* out = (float*)d_out;                  // [512,28,1]

    float* ws  = (float*)d_ws;
    float* Wt2 = ws;                         // 512*512*4 = 1,048,576 floats (4 MB)
    float* hT0 = Wt2 + HH * HH * 4;          // 262,144 floats
    float* hT1 = hT0 + HH * HH;              // 262,144 floats
    float* cT  = hT1 + HH * HH;              // 262,144 floats
    // total ws use: 7,340,032 bytes

    prep_kernel<<<dim3(1024), dim3(256), 0, stream>>>(W_hh, Wt2, hT0, hT1, cT);

    float* hbuf[2] = {hT0, hT1};
    for (int t = 0; t < TT; ++t) {
        lstm_step<<<dim3(32, 8), dim3(256), 0, stream>>>(
            Wt2, hbuf[t & 1], hbuf[(t + 1) & 1], cT,
            seq, W_ih, b_ih, b_hh, t);
    }

    // after 256 steps, final h lives in hbuf[256 & 1] == hT0
    fc_kernel<<<dim3(512), dim3(256), 0, stream>>>(
        hT0, fc1_w, fc1_b, fc2_w, fc2_b, out);
}

// Round 2
// 3393.296 us; speedup vs baseline: 3.2973x; 3.2973x over previous
//
#include <hip/hip_runtime.h>
#include <hip/hip_bf16.h>
#include <math.h>

// B=512, T=256, H=512, 4H=2048 gate cols, HALF=256, TGT=28
#define BB   512
#define TT   256
#define HH   512
#define NCOL 2048
#define HALF 256
#define TGT  28

typedef short short8 __attribute__((ext_vector_type(8)));
typedef float f32x4  __attribute__((ext_vector_type(4)));

__device__ __forceinline__ float bf2f(unsigned short u) {
    union { unsigned int i; float f; } v; v.i = ((unsigned int)u) << 16; return v.f;
}
__device__ __forceinline__ unsigned short f2bf(float x) {
    union { float f; unsigned int i; } v; v.f = x;
    unsigned int u = v.i;
    return (unsigned short)((u + 0x7FFFu + ((u >> 16) & 1u)) >> 16);
}
__device__ __forceinline__ float sigmoidf_(float x) {
    return 1.0f / (1.0f + __expf(-x));
}
__device__ __forceinline__ float tanhf_(float x) {
    x = fminf(fmaxf(x, -15.0f), 15.0f);
    float e = __expf(-2.0f * x);
    return (1.0f - e) / (1.0f + e);
}

// Fragment-order address for element (row r, k) of a 16-wide M/N tile:
// plane layout [tile16][kchunk32][ (quad*16 + r15)*8 + k7 ]; tile stride 8192.
__device__ __forceinline__ int frag_addr(int r, int k) {
    return (r >> 4) * 8192 + (k >> 5) * 512 + ((((k >> 3) & 3) << 4) + (r & 15)) * 8 + (k & 7);
}

// prep: split W_hh into hi/lo bf16 planes in B-fragment order (col n = j*4+g),
// zero h-plane buffer 0 and c. Runs every call (ws is re-poisoned).
__global__ __launch_bounds__(256) void prep_kernel(
    const float* __restrict__ Whh,
    unsigned short* __restrict__ Whi, unsigned short* __restrict__ Wlo,
    unsigned short* __restrict__ h0hi, unsigned short* __restrict__ h0lo,
    float* __restrict__ cT)
{
    int tid = blockIdx.x * 256 + threadIdx.x;   // grid 1024 -> 262144 threads
    h0hi[tid] = 0; h0lo[tid] = 0;               // bf16 zero
    cT[tid] = 0.0f;
    for (int e = tid; e < NCOL * HH; e += 262144) {
        int n = e >> 9;            // gate col 0..2047  (n = j*4+g)
        int k = e & (HH - 1);
        int j = n >> 2, g = n & 3;
        float w = Whh[(g * HH + j) * HH + k];
        unsigned short hi = f2bf(w);
        float lo = w - bf2f(hi);
        int a = frag_addr(n, k);
        Whi[a] = hi;
        Wlo[a] = f2bf(lo);
    }
}

// One LSTM step. Grid (32,16) = 512 blocks (2/CU), 256 threads (4 waves).
// Block tile: 32 b x 64 cols. Wave tile: 16 b x 32 cols (2 mfma N-tiles).
// Split-precision: acc += Ahi*Bhi + Ahi*Blo + Alo*Bhi (3 MFMAs per tile).
__global__ __launch_bounds__(256, 2) void lstm_step(
    const unsigned short* __restrict__ Whi, const unsigned short* __restrict__ Wlo,
    const unsigned short* __restrict__ hphi, const unsigned short* __restrict__ hplo,
    unsigned short* __restrict__ hnhi, unsigned short* __restrict__ hnlo,
    float* __restrict__ cT,
    const float* __restrict__ seq,
    const float* __restrict__ wih,
    const float* __restrict__ bih, const float* __restrict__ bhh,
    int t)
{
    const int tid   = threadIdx.x;
    const int lane  = tid & 63;
    const int wave  = tid >> 6;
    const int wm    = wave >> 1, wn = wave & 1;
    const int col16 = lane & 15, quad = lane >> 4;

    const int m0 = blockIdx.y * 32 + wm * 16;   // wave batch-row offset
    const int n0 = blockIdx.x * 64 + wn * 32;   // wave gate-col offset

    // acc init = bias[n] + x[b] * wih[n]  (rank-1 input term + fused bias)
    float xr[4];
    #pragma unroll
    for (int r = 0; r < 4; ++r)
        xr[r] = seq[(m0 + quad * 4 + r) * TT + t];

    f32x4 acc[2];
    #pragma unroll
    for (int nt = 0; nt < 2; ++nt) {
        int n   = n0 + nt * 16 + col16;
        int src = (n & 3) * HH + (n >> 2);      // original row g*H+j
        float bn = bih[src] + bhh[src];
        float wn_ = wih[src];
        #pragma unroll
        for (int r = 0; r < 4; ++r)
            acc[nt][r] = bn + xr[r] * wn_;
    }

    // K-loop: everything pre-laid-out in fragment order -> lane-contiguous 16B loads
    const int abase  = (m0 >> 4) * 8192 + lane * 8;
    const int bbase0 = (n0 >> 4) * 8192 + lane * 8;
    const int bbase1 = bbase0 + 8192;

    #pragma unroll 4
    for (int kc = 0; kc < 16; ++kc) {
        int ao = abase + kc * 512;
        short8 ahi = *(const short8*)(hphi + ao);
        short8 alo = *(const short8*)(hplo + ao);
        int bo0 = bbase0 + kc * 512, bo1 = bbase1 + kc * 512;
        short8 b0h = *(const short8*)(Whi + bo0);
        short8 b0l = *(const short8*)(Wlo + bo0);
        short8 b1h = *(const short8*)(Whi + bo1);
        short8 b1l = *(const short8*)(Wlo + bo1);
        acc[0] = __builtin_amdgcn_mfma_f32_16x16x32_bf16(ahi, b0h, acc[0], 0, 0, 0);
        acc[0] = __builtin_amdgcn_mfma_f32_16x16x32_bf16(ahi, b0l, acc[0], 0, 0, 0);
        acc[0] = __builtin_amdgcn_mfma_f32_16x16x32_bf16(alo, b0h, acc[0], 0, 0, 0);
        acc[1] = __builtin_amdgcn_mfma_f32_16x16x32_bf16(ahi, b1h, acc[1], 0, 0, 0);
        acc[1] = __builtin_amdgcn_mfma_f32_16x16x32_bf16(ahi, b1l, acc[1], 0, 0, 0);
        acc[1] = __builtin_amdgcn_mfma_f32_16x16x32_bf16(alo, b1h, acc[1], 0, 0, 0);
    }

    // Epilogue: gather 4 gates per (b,j) via LDS, update c/h, re-split h.
    __shared__ float gbuf[32][64];
    #pragma unroll
    for (int nt = 0; nt < 2; ++nt)
        #pragma unroll
        for (int r = 0; r < 4; ++r)
            gbuf[wm * 16 + quad * 4 + r][wn * 32 + nt * 16 + col16] = acc[nt][r];
    __syncthreads();

    const int b0 = blockIdx.y * 32;
    const int j0 = blockIdx.x * 16;
    #pragma unroll
    for (int pp = 0; pp < 2; ++pp) {
        int p  = tid + pp * 256;
        int jj = p & 15, bb = p >> 4;
        f32x4 gt = *(const f32x4*)(&gbuf[bb][jj * 4]);
        int b = b0 + bb, jg = j0 + jj;
        float i_ = sigmoidf_(gt[0]);
        float f_ = sigmoidf_(gt[1]);
        float g_ = tanhf_(gt[2]);
        float o_ = sigmoidf_(gt[3]);
        int ca = b * HH + jg;
        float cn = f_ * cT[ca] + i_ * g_;
        cT[ca] = cn;
        float h = o_ * tanhf_(cn);
        unsigned short hhi = f2bf(h);
        float lo = h - bf2f(hhi);
        int ha = frag_addr(b, jg);
        hnhi[ha] = hhi;
        hnlo[ha] = f2bf(lo);
    }
}

// FC tail: hid = relu(h @ fc1_w.T + b); out = hid @ fc2_w.T + b. One block per b.
__global__ __launch_bounds__(256) void fc_kernel(
    const unsigned short* __restrict__ hhi, const unsigned short* __restrict__ hlo,
    const float* __restrict__ fc1w, const float* __restrict__ fc1b,
    const float* __restrict__ fc2w, const float* __restrict__ fc2b,
    float* __restrict__ out)
{
    __shared__ float hS[HH];
    __shared__ float hidS[HALF];
    const int b = blockIdx.x, tid = threadIdx.x;

    for (int k = tid; k < HH; k += 256) {
        int a = frag_addr(b, k);
        hS[k] = bf2f(hhi[a]) + bf2f(hlo[a]);
    }
    __syncthreads();

    float acc = fc1b[tid];
    const float4* wrow = (const float4*)(fc1w + tid * HH);
    #pragma unroll 4
    for (int k4 = 0; k4 < HH / 4; ++k4) {
        float4 w = wrow[k4];
        acc += w.x * hS[k4 * 4] + w.y * hS[k4 * 4 + 1]
             + w.z * hS[k4 * 4 + 2] + w.w * hS[k4 * 4 + 3];
    }
    hidS[tid] = fmaxf(acc, 0.0f);
    __syncthreads();

    if (tid < TGT) {
        float a2 = fc2b[tid];
        const float4* w2 = (const float4*)(fc2w + tid * HALF);
        #pragma unroll 4
        for (int k4 = 0; k4 < HALF / 4; ++k4) {
            float4 w = w2[k4];
            a2 += w.x * hidS[k4 * 4] + w.y * hidS[k4 * 4 + 1]
                + w.z * hidS[k4 * 4 + 2] + w.w * hidS[k4 * 4 + 3];
        }
        out[b * TGT + tid] = a2;
    }
}

extern "C" void kernel_launch(void* const* d_in, const int* in_sizes, int n_in,
                              void* d_out, int out_size, void* d_ws, size_t ws_size,
                              hipStream_t stream)
{
    const float* seq   = (const float*)d_in[0];
    const float* W_ih  = (const float*)d_in[1];
    const float* W_hh  = (const float*)d_in[2];
    const float* b_ih  = (const float*)d_in[3];
    const float* b_hh  = (const float*)d_in[4];
    const float* fc1_w = (const float*)d_in[5];
    const float* fc1_b = (const float*)d_in[6];
    const float* fc2_w = (const float*)d_in[7];
    const float* fc2_b = (const float*)d_in[8];
    float* out = (float*)d_out;

    // ws layout (total 7,340,032 B — same footprint as round-1):
    unsigned short* us = (unsigned short*)d_ws;
    unsigned short* Whi  = us;                  // 1,048,576 shorts
    unsigned short* Wlo  = us + 1048576;        // 1,048,576
    unsigned short* h0hi = us + 2097152;        // 262,144
    unsigned short* h0lo = us + 2359296;
    unsigned short* h1hi = us + 2621440;
    unsigned short* h1lo = us + 2883584;        // ends at 3,145,728 shorts
    float* cT = (float*)(us + 3145728);         // 262,144 floats

    prep_kernel<<<dim3(1024), dim3(256), 0, stream>>>(W_hh, Whi, Wlo, h0hi, h0lo, cT);

    unsigned short* hhiB[2] = {h0hi, h1hi};
    unsigned short* hloB[2] = {h0lo, h1lo};
    for (int t = 0; t < TT; ++t) {
        lstm_step<<<dim3(32, 16), dim3(256), 0, stream>>>(
            Whi, Wlo,
            hhiB[t & 1], hloB[t & 1],
            hhiB[(t + 1) & 1], hloB[(t + 1) & 1],
            cT, seq, W_ih, b_ih, b_hh, t);
    }

    // final h is in buffer 0 (t=255 writes (255+1)&1 = 0)
    fc_kernel<<<dim3(512), dim3(256), 0, stream>>>(
        h0hi, h0lo, fc1_w, fc1_b, fc2_w, fc2_b, out);
}